// Round 15
// baseline (585.303 us; speedup 1.0000x reference)
//
#include <hip/hip_runtime.h>
#include <hip/hip_bf16.h>

#define S 4096
#define DM 768
#define NH 12
#define DK 64
#define RPARTS 8
#define RCHUNK (S / RPARTS)

typedef __bf16 bf16x8 __attribute__((ext_vector_type(8)));
typedef __bf16 bf16x4 __attribute__((ext_vector_type(4)));
typedef float f32x4 __attribute__((ext_vector_type(4)));
using bf16 = __hip_bfloat16;

__device__ inline bf16x8 load_frag(const bf16* p) {
    return *reinterpret_cast<const bf16x8*>(p);
}

// Detect input dtype (f32 vs bf16) from bit patterns; flag=1 -> f32.
__global__ void k_detect(const unsigned int* __restrict__ q, int* __restrict__ flag) {
    const int lane = threadIdx.x;  // 64 threads
    int cnt = 0;
    for (int i = lane; i < 1024; i += 64) {
        const unsigned int w = q[i];
        const int e = (w >> 7) & 0xFF;
        if (e >= 192 || (e > 0 && e < 64)) cnt++;
    }
    for (int m = 1; m < 64; m <<= 1) cnt += __shfl_xor(cnt, m, 64);
    if (lane == 0) flag[0] = (cnt > 64) ? 1 : 0;
}

struct CastArgs {
    const void* s[11];
    bf16* d[11];
    int n[11];
};

__global__ __launch_bounds__(256) void k_cast_all(CastArgs a, const int* __restrict__ flag) {
    const int t = blockIdx.y;
    const void* src = a.s[t];
    bf16* dst = a.d[t];
    const int n = a.n[t];
    const int isf32 = flag[0];
    const int stride = gridDim.x * 256 * 8;
    for (int i = (blockIdx.x * 256 + threadIdx.x) * 8; i < n; i += stride) {
        if (isf32) {
            const float* s = (const float*)src + i;
            float4 x = *(const float4*)(s);
            float4 y = *(const float4*)(s + 4);
            bf16x8 o;
            o[0] = (__bf16)x.x; o[1] = (__bf16)x.y; o[2] = (__bf16)x.z; o[3] = (__bf16)x.w;
            o[4] = (__bf16)y.x; o[5] = (__bf16)y.y; o[6] = (__bf16)y.z; o[7] = (__bf16)y.w;
            *reinterpret_cast<bf16x8*>(dst + i) = o;
        } else {
            *reinterpret_cast<bf16x8*>(dst + i) =
                *reinterpret_cast<const bf16x8*>((const __bf16*)src + i);
        }
    }
}

// x @ W^T + b core. mode 0/1: head-split [H][S][DK]; mode 2: transposed [DM][S].
__device__ inline void proj_body(
    const bf16* __restrict__ X, const bf16* __restrict__ W,
    const bf16* __restrict__ bias, void* __restrict__ dstv, int mode, int isf32)
{
    const int lane = threadIdx.x & 63;
    const int w    = threadIdx.x >> 6;
    const int lr   = lane & 15, lg = lane >> 4;
    const int rbase = blockIdx.x * 64 + w * 16;
    const int nbase = blockIdx.y * 64;

    f32x4 acc[4] = {};
    const bf16* xrow = X + (size_t)(rbase + lr) * DM + lg * 8;
    for (int kk = 0; kk < DM; kk += 32) {
        bf16x8 a = load_frag(xrow + kk);
#pragma unroll
        for (int nt = 0; nt < 4; ++nt) {
            bf16x8 b = load_frag(W + (size_t)(nbase + nt * 16 + lr) * DM + kk + lg * 8);
            acc[nt] = __builtin_amdgcn_mfma_f32_16x16x32_bf16(a, b, acc[nt], 0, 0, 0);
        }
    }
#pragma unroll
    for (int nt = 0; nt < 4; ++nt) {
        const int col = nbase + nt * 16 + lr;
        const float bv = __bfloat162float(bias[col]);
#pragma unroll
        for (int r = 0; r < 4; ++r) {
            const int row = rbase + lg * 4 + r;
            const float v = acc[nt][r] + bv;
            size_t off;
            if (mode == 2) off = (size_t)col * S + row;
            else           off = (size_t)(col >> 6) * (S * DK) + (size_t)row * DK + (col & 63);
            ((bf16*)dstv)[off] = __float2bfloat16(v);
        }
    }
}

// Fused Q/K/V projections: blockIdx.z selects tensor (0->qh, 1->kh, 2->vt).
__global__ __launch_bounds__(256) void k_proj_qkv(
    const bf16* __restrict__ Qc, const bf16* __restrict__ Kc, const bf16* __restrict__ Vc,
    const bf16* __restrict__ Wq, const bf16* __restrict__ Wk, const bf16* __restrict__ Wv,
    const bf16* __restrict__ bq, const bf16* __restrict__ bk, const bf16* __restrict__ bv,
    bf16* __restrict__ qh, bf16* __restrict__ kh, bf16* __restrict__ vt,
    const int* __restrict__ flag)
{
    const int z = blockIdx.z;
    const bf16* X = (z == 0) ? Qc : (z == 1) ? Kc : Vc;
    const bf16* W = (z == 0) ? Wq : (z == 1) ? Wk : Wv;
    const bf16* B = (z == 0) ? bq : (z == 1) ? bk : bv;
    bf16* D      = (z == 0) ? qh : (z == 1) ? kh : vt;
    proj_body(X, W, B, D, (z == 2) ? 2 : 0, flag[0]);
}

// Output projection: out = ctx @ Wo^T + bo, dtype per flag.
__global__ __launch_bounds__(256) void k_proj_out(
    const bf16* __restrict__ ctx, const bf16* __restrict__ W,
    const bf16* __restrict__ bias, void* __restrict__ dstv,
    const int* __restrict__ flag)
{
    const int isf32 = flag[0];
    const int lane = threadIdx.x & 63;
    const int w    = threadIdx.x >> 6;
    const int lr   = lane & 15, lg = lane >> 4;
    const int rbase = blockIdx.x * 64 + w * 16;
    const int nbase = blockIdx.y * 64;

    f32x4 acc[4] = {};
    const bf16* xrow = ctx + (size_t)(rbase + lr) * DM + lg * 8;
    for (int kk = 0; kk < DM; kk += 32) {
        bf16x8 a = load_frag(xrow + kk);
#pragma unroll
        for (int nt = 0; nt < 4; ++nt) {
            bf16x8 b = load_frag(W + (size_t)(nbase + nt * 16 + lr) * DM + kk + lg * 8);
            acc[nt] = __builtin_amdgcn_mfma_f32_16x16x32_bf16(a, b, acc[nt], 0, 0, 0);
        }
    }
#pragma unroll
    for (int nt = 0; nt < 4; ++nt) {
        const int col = nbase + nt * 16 + lr;
        const float bv = __bfloat162float(bias[col]);
#pragma unroll
        for (int r = 0; r < 4; ++r) {
            const int row = rbase + lg * 4 + r;
            const float v = acc[nt][r] + bv;
            const size_t off = (size_t)row * DM + col;
            if (isf32) ((float*)dstv)[off] = v;
            else       ((bf16*)dstv)[off] = __float2bfloat16(v);
        }
    }
}

// Partial row sums of exp(scores/8). (verified R9)
__global__ __launch_bounds__(256) void k_rowsum(
    const bf16* __restrict__ qh, const bf16* __restrict__ kh,
    float* __restrict__ rs)
{
    const int lane = threadIdx.x & 63;
    const int w    = threadIdx.x >> 6;
    const int lr   = lane & 15;
    const int lg   = lane >> 4;
    const int h    = blockIdx.y;
    const int part = blockIdx.z;
    const int qw   = blockIdx.x * 256 + w * 64;

    const bf16* qb = qh + (size_t)h * (S * DK);
    const bf16* kb = kh + (size_t)h * (S * DK);
    bf16x8 aq[4][2];
#pragma unroll
    for (int qs = 0; qs < 4; ++qs) {
        aq[qs][0] = load_frag(qb + (size_t)(qw + qs * 16 + lr) * DK + lg * 8);
        aq[qs][1] = load_frag(qb + (size_t)(qw + qs * 16 + lr) * DK + 32 + lg * 8);
    }

    float s[4] = {0.f, 0.f, 0.f, 0.f};
    for (int kp = part * RCHUNK; kp < part * RCHUNK + RCHUNK; kp += 16) {
        bf16x8 b0 = load_frag(kb + (size_t)(kp + lr) * DK + lg * 8);
        bf16x8 b1 = load_frag(kb + (size_t)(kp + lr) * DK + 32 + lg * 8);
#pragma unroll
        for (int qs = 0; qs < 4; ++qs) {
            f32x4 d = {};
            d = __builtin_amdgcn_mfma_f32_16x16x32_bf16(b0, aq[qs][0], d, 0, 0, 0);
            d = __builtin_amdgcn_mfma_f32_16x16x32_bf16(b1, aq[qs][1], d, 0, 0, 0);
            s[qs] += __expf(d[0] * 0.125f) + __expf(d[1] * 0.125f) +
                     __expf(d[2] * 0.125f) + __expf(d[3] * 0.125f);
        }
    }
#pragma unroll
    for (int qs = 0; qs < 4; ++qs) {
        float v = s[qs];
        v += __shfl_xor(v, 16, 64);
        v += __shfl_xor(v, 32, 64);
        if (lg == 0)
            rs[((size_t)part * NH + h) * S + qw + qs * 16 + lr] = v;
    }
}

// R13-verified body (2-wave blocks, 32 q-rows/wave, 4-tile 256-col staging,
// V-prefetch, 1KB-row flush, no barrier). SINGLE CHANGE vs R13: the f32
// flush uses plain TEMPORAL stores (nontemporal was capping write BW; the
// harness fill kernel proves temporal dense stores hit 6.7 TB/s).
__global__ __launch_bounds__(128) void k_attn(
    const bf16* __restrict__ qh, const bf16* __restrict__ kh,
    const bf16* __restrict__ vt, const float* __restrict__ rs,
    void* __restrict__ doutv, bf16* __restrict__ ctx,
    const int* __restrict__ flag)
{
    __shared__ __align__(16) bf16 Plds[2][2][16][264];
    const int isf32 = flag[0];
    const int lane = threadIdx.x & 63;
    const int w    = threadIdx.x >> 6;           // 0..1
    const int lr   = lane & 15, lg = lane >> 4;
    const int h    = blockIdx.y;
    const int q0w  = blockIdx.x * 64 + w * 32;   // wave's 32-q base

    const bf16* qb = qh + (size_t)h * (S * DK);
    const bf16* kb = kh + (size_t)h * (S * DK);
    const bf16* vb = vt + (size_t)h * (S * DK);

    bf16x8 aq[2][2];
    float  linv[2];
#pragma unroll
    for (int qs = 0; qs < 2; ++qs) {
        const int qr = q0w + qs * 16 + lr;
        aq[qs][0] = load_frag(qb + (size_t)qr * DK + lg * 8);
        aq[qs][1] = load_frag(qb + (size_t)qr * DK + 32 + lg * 8);
        float ssum = 0.f;
#pragma unroll
        for (int p = 0; p < RPARTS; ++p)
            ssum += rs[((size_t)p * NH + h) * S + qr];
        linv[qs] = -__logf(ssum);   // p = exp(s/8 + ln(1/sum))
    }

    float* poutF = (float*)doutv + (size_t)S * DM + (size_t)h * S * S;
    bf16*  poutB = (bf16*)doutv  + (size_t)S * DM + (size_t)h * S * S;

    f32x4 acc[2][4] = {};
    for (int g = 0; g < S / 256; ++g) {          // 16 groups of 4 tiles
#pragma unroll
        for (int tt = 0; tt < 4; ++tt) {
            const int kt = g * 256 + tt * 64;
            const int cb = tt * 64;              // column base in Plds
            // ---- V prefetch for this tile (independent of P) ----
            bf16x8 vv[4][2];
#pragma unroll
            for (int dt = 0; dt < 4; ++dt) {
                vv[dt][0] = load_frag(vb + (size_t)(dt * 16 + lr) * S + kt + lg * 8);
                vv[dt][1] = load_frag(vb + (size_t)(dt * 16 + lr) * S + kt + 32 + lg * 8);
            }
            // ---- QK^T (swapped: D rows = k, cols = q), exp, stage bf16 ----
#pragma unroll
            for (int sub = 0; sub < 4; ++sub) {
                const int kp = kt + sub * 16;
                bf16x8 b0 = load_frag(kb + (size_t)(kp + lr) * DK + lg * 8);
                bf16x8 b1 = load_frag(kb + (size_t)(kp + lr) * DK + 32 + lg * 8);
#pragma unroll
                for (int qs = 0; qs < 2; ++qs) {
                    f32x4 d = {};
                    d = __builtin_amdgcn_mfma_f32_16x16x32_bf16(b0, aq[qs][0], d, 0, 0, 0);
                    d = __builtin_amdgcn_mfma_f32_16x16x32_bf16(b1, aq[qs][1], d, 0, 0, 0);
                    bf16x4 pv;
                    pv[0] = (__bf16)__expf(__builtin_fmaf(d[0], 0.125f, linv[qs]));
                    pv[1] = (__bf16)__expf(__builtin_fmaf(d[1], 0.125f, linv[qs]));
                    pv[2] = (__bf16)__expf(__builtin_fmaf(d[2], 0.125f, linv[qs]));
                    pv[3] = (__bf16)__expf(__builtin_fmaf(d[3], 0.125f, linv[qs]));
                    *reinterpret_cast<bf16x4*>(
                        &Plds[w][qs][lr][cb + sub * 16 + 4 * lg]) = pv;
                }
            }
            // ---- PV on this 64-k tile (prefetched V, shared across qs) ----
            bf16x8 ap[2][2];
#pragma unroll
            for (int qs = 0; qs < 2; ++qs) {
                ap[qs][0] = *reinterpret_cast<const bf16x8*>(&Plds[w][qs][lr][cb + lg * 8]);
                ap[qs][1] = *reinterpret_cast<const bf16x8*>(&Plds[w][qs][lr][cb + 32 + lg * 8]);
            }
#pragma unroll
            for (int dt = 0; dt < 4; ++dt) {
#pragma unroll
                for (int qs = 0; qs < 2; ++qs) {
                    acc[qs][dt] = __builtin_amdgcn_mfma_f32_16x16x32_bf16(ap[qs][0], vv[dt][0], acc[qs][dt], 0, 0, 0);
                    acc[qs][dt] = __builtin_amdgcn_mfma_f32_16x16x32_bf16(ap[qs][1], vv[dt][1], acc[qs][dt], 0, 0, 0);
                }
            }
        }
        // ---- flush 4 tiles: 32 rows x 256 cols; 1KB row per store, TEMPORAL ----
        const int ktbase = g * 256;
        if (isf32) {
#pragma unroll
            for (int j = 0; j < 32; ++j) {
                const int qs = j >> 4, rr = j & 15;
                bf16x4 x = *reinterpret_cast<const bf16x4*>(&Plds[w][qs][rr][lane * 4]);
                f32x4 o;
                o[0] = (float)x[0]; o[1] = (float)x[1];
                o[2] = (float)x[2]; o[3] = (float)x[3];
                *reinterpret_cast<f32x4*>(
                    poutF + (size_t)(q0w + j) * S + ktbase + lane * 4) = o;
            }
        } else {
#pragma unroll
            for (int j = 0; j < 32; ++j) {
                const int qs = j >> 4, rr = j & 15;
                bf16x4 x = *reinterpret_cast<const bf16x4*>(&Plds[w][qs][rr][lane * 4]);
                *reinterpret_cast<bf16x4*>(
                    poutB + (size_t)(q0w + j) * S + ktbase + lane * 4) = x;
            }
        }
    }
    // epilogue: ctx[q][h*64+d] (bf16), full k-range per q -> direct write
#pragma unroll
    for (int qs = 0; qs < 2; ++qs)
#pragma unroll
        for (int dt = 0; dt < 4; ++dt)
#pragma unroll
            for (int r = 0; r < 4; ++r)
                ctx[(size_t)(q0w + qs * 16 + 4 * lg + r) * DM + h * DK + dt * 16 + lr] =
                    __float2bfloat16(acc[qs][dt][r]);
}

extern "C" void kernel_launch(void* const* d_in, const int* in_sizes, int n_in,
                              void* d_out, int out_size, void* d_ws, size_t ws_size,
                              hipStream_t stream) {
    char* wsb = (char*)d_ws;
    int*   flag = (int*)wsb;                                    // 16 B
    float* rs   = (float*)(wsb + 16);                           // RPARTS*NH*S f32
    bf16*  conv = (bf16*)(wsb + 16 + (size_t)RPARTS * NH * S * 4);

    const size_t nQ = (size_t)S * DM, nW = (size_t)DM * DM, nB = DM;
    bf16* Qc  = conv;
    bf16* Kc  = Qc + nQ;
    bf16* Vc  = Kc + nQ;
    bf16* Wqc = Vc + nQ;
    bf16* Wkc = Wqc + nW;
    bf16* Wvc = Wkc + nW;
    bf16* Woc = Wvc + nW;
    bf16* bqc = Woc + nW;
    bf16* bkc = bqc + nB;
    bf16* bvc = bkc + nB;
    bf16* boc = bvc + nB;
    bf16* qh  = boc + nB;
    bf16* kh  = qh + nQ;
    bf16* vt  = kh + nQ;
    // alias (Qc dead after projections): ctx = nQ bf16
    bf16* ctx = Qc;

    const size_t need = (size_t)((char*)(vt + nQ) - wsb);
    if (ws_size < need) return;

    dim3 blk(256);
    k_detect<<<1, 64, 0, stream>>>((const unsigned int*)d_in[0], flag);

    CastArgs ca;
    ca.s[0] = d_in[0];  ca.d[0] = Qc;   ca.n[0] = (int)nQ;
    ca.s[1] = d_in[1];  ca.d[1] = Kc;   ca.n[1] = (int)nQ;
    ca.s[2] = d_in[2];  ca.d[2] = Vc;   ca.n[2] = (int)nQ;
    ca.s[3] = d_in[3];  ca.d[3] = Wqc;  ca.n[3] = (int)nW;
    ca.s[4] = d_in[5];  ca.d[4] = Wkc;  ca.n[4] = (int)nW;
    ca.s[5] = d_in[7];  ca.d[5] = Wvc;  ca.n[5] = (int)nW;
    ca.s[6] = d_in[9];  ca.d[6] = Woc;  ca.n[6] = (int)nW;
    ca.s[7] = d_in[4];  ca.d[7] = bqc;  ca.n[7] = (int)nB;
    ca.s[8] = d_in[6];  ca.d[8] = bkc;  ca.n[8] = (int)nB;
    ca.s[9] = d_in[8];  ca.d[9] = bvc;  ca.n[9] = (int)nB;
    ca.s[10] = d_in[10]; ca.d[10] = boc; ca.n[10] = (int)nB;
    k_cast_all<<<dim3(512, 11), blk, 0, stream>>>(ca, flag);

    k_proj_qkv<<<dim3(S / 64, DM / 64, 3), blk, 0, stream>>>(
        Qc, Kc, Vc, Wqc, Wkc, Wvc, bqc, bkc, bvc, qh, kh, vt, flag);
    k_rowsum<<<dim3(S / 256, NH, RPARTS), blk, 0, stream>>>(qh, kh, rs);
    k_attn<<<dim3(S / 64, NH), dim3(128), 0, stream>>>(qh, kh, vt, rs, d_out, ctx, flag);
    k_proj_out<<<dim3(S / 64, DM / 64), blk, 0, stream>>>(ctx, Woc, boc, d_out, flag);
}

// Round 16
// 446.974 us; speedup vs baseline: 1.3095x; 1.3095x over previous
//
#include <hip/hip_runtime.h>
#include <hip/hip_bf16.h>

#define S 4096
#define DM 768
#define NH 12
#define DK 64
#define RPARTS 8
#define RCHUNK (S / RPARTS)

typedef __bf16 bf16x8 __attribute__((ext_vector_type(8)));
typedef __bf16 bf16x4 __attribute__((ext_vector_type(4)));
typedef float f32x4 __attribute__((ext_vector_type(4)));
using bf16 = __hip_bfloat16;

__device__ inline bf16x8 load_frag(const bf16* p) {
    return *reinterpret_cast<const bf16x8*>(p);
}

// Detect input dtype (f32 vs bf16) from bit patterns; flag=1 -> f32.
__global__ void k_detect(const unsigned int* __restrict__ q, int* __restrict__ flag) {
    const int lane = threadIdx.x;  // 64 threads
    int cnt = 0;
    for (int i = lane; i < 1024; i += 64) {
        const unsigned int w = q[i];
        const int e = (w >> 7) & 0xFF;
        if (e >= 192 || (e > 0 && e < 64)) cnt++;
    }
    for (int m = 1; m < 64; m <<= 1) cnt += __shfl_xor(cnt, m, 64);
    if (lane == 0) flag[0] = (cnt > 64) ? 1 : 0;
}

struct CastArgs {
    const void* s[11];
    bf16* d[11];
    int n[11];
};

__global__ __launch_bounds__(256) void k_cast_all(CastArgs a, const int* __restrict__ flag) {
    const int t = blockIdx.y;
    const void* src = a.s[t];
    bf16* dst = a.d[t];
    const int n = a.n[t];
    const int isf32 = flag[0];
    const int stride = gridDim.x * 256 * 8;
    for (int i = (blockIdx.x * 256 + threadIdx.x) * 8; i < n; i += stride) {
        if (isf32) {
            const float* s = (const float*)src + i;
            float4 x = *(const float4*)(s);
            float4 y = *(const float4*)(s + 4);
            bf16x8 o;
            o[0] = (__bf16)x.x; o[1] = (__bf16)x.y; o[2] = (__bf16)x.z; o[3] = (__bf16)x.w;
            o[4] = (__bf16)y.x; o[5] = (__bf16)y.y; o[6] = (__bf16)y.z; o[7] = (__bf16)y.w;
            *reinterpret_cast<bf16x8*>(dst + i) = o;
        } else {
            *reinterpret_cast<bf16x8*>(dst + i) =
                *reinterpret_cast<const bf16x8*>((const __bf16*)src + i);
        }
    }
}

// x @ W^T + b core. mode 0/1: head-split [H][S][DK]; mode 2: transposed [DM][S].
__device__ inline void proj_body(
    const bf16* __restrict__ X, const bf16* __restrict__ W,
    const bf16* __restrict__ bias, void* __restrict__ dstv, int mode, int isf32)
{
    const int lane = threadIdx.x & 63;
    const int w    = threadIdx.x >> 6;
    const int lr   = lane & 15, lg = lane >> 4;
    const int rbase = blockIdx.x * 64 + w * 16;
    const int nbase = blockIdx.y * 64;

    f32x4 acc[4] = {};
    const bf16* xrow = X + (size_t)(rbase + lr) * DM + lg * 8;
    for (int kk = 0; kk < DM; kk += 32) {
        bf16x8 a = load_frag(xrow + kk);
#pragma unroll
        for (int nt = 0; nt < 4; ++nt) {
            bf16x8 b = load_frag(W + (size_t)(nbase + nt * 16 + lr) * DM + kk + lg * 8);
            acc[nt] = __builtin_amdgcn_mfma_f32_16x16x32_bf16(a, b, acc[nt], 0, 0, 0);
        }
    }
#pragma unroll
    for (int nt = 0; nt < 4; ++nt) {
        const int col = nbase + nt * 16 + lr;
        const float bv = __bfloat162float(bias[col]);
#pragma unroll
        for (int r = 0; r < 4; ++r) {
            const int row = rbase + lg * 4 + r;
            const float v = acc[nt][r] + bv;
            size_t off;
            if (mode == 2) off = (size_t)col * S + row;
            else           off = (size_t)(col >> 6) * (S * DK) + (size_t)row * DK + (col & 63);
            ((bf16*)dstv)[off] = __float2bfloat16(v);
        }
    }
}

// Fused Q/K/V projections: blockIdx.z selects tensor (0->qh, 1->kh, 2->vt).
__global__ __launch_bounds__(256) void k_proj_qkv(
    const bf16* __restrict__ Qc, const bf16* __restrict__ Kc, const bf16* __restrict__ Vc,
    const bf16* __restrict__ Wq, const bf16* __restrict__ Wk, const bf16* __restrict__ Wv,
    const bf16* __restrict__ bq, const bf16* __restrict__ bk, const bf16* __restrict__ bv,
    bf16* __restrict__ qh, bf16* __restrict__ kh, bf16* __restrict__ vt,
    const int* __restrict__ flag)
{
    const int z = blockIdx.z;
    const bf16* X = (z == 0) ? Qc : (z == 1) ? Kc : Vc;
    const bf16* W = (z == 0) ? Wq : (z == 1) ? Wk : Wv;
    const bf16* B = (z == 0) ? bq : (z == 1) ? bk : bv;
    bf16* D      = (z == 0) ? qh : (z == 1) ? kh : vt;
    proj_body(X, W, B, D, (z == 2) ? 2 : 0, flag[0]);
}

// Output projection: out = ctx @ Wo^T + bo, dtype per flag.
__global__ __launch_bounds__(256) void k_proj_out(
    const bf16* __restrict__ ctx, const bf16* __restrict__ W,
    const bf16* __restrict__ bias, void* __restrict__ dstv,
    const int* __restrict__ flag)
{
    const int isf32 = flag[0];
    const int lane = threadIdx.x & 63;
    const int w    = threadIdx.x >> 6;
    const int lr   = lane & 15, lg = lane >> 4;
    const int rbase = blockIdx.x * 64 + w * 16;
    const int nbase = blockIdx.y * 64;

    f32x4 acc[4] = {};
    const bf16* xrow = ctx + (size_t)(rbase + lr) * DM + lg * 8;
    for (int kk = 0; kk < DM; kk += 32) {
        bf16x8 a = load_frag(xrow + kk);
#pragma unroll
        for (int nt = 0; nt < 4; ++nt) {
            bf16x8 b = load_frag(W + (size_t)(nbase + nt * 16 + lr) * DM + kk + lg * 8);
            acc[nt] = __builtin_amdgcn_mfma_f32_16x16x32_bf16(a, b, acc[nt], 0, 0, 0);
        }
    }
#pragma unroll
    for (int nt = 0; nt < 4; ++nt) {
        const int col = nbase + nt * 16 + lr;
        const float bv = __bfloat162float(bias[col]);
#pragma unroll
        for (int r = 0; r < 4; ++r) {
            const int row = rbase + lg * 4 + r;
            const float v = acc[nt][r] + bv;
            const size_t off = (size_t)row * DM + col;
            if (isf32) ((float*)dstv)[off] = v;
            else       ((bf16*)dstv)[off] = __float2bfloat16(v);
        }
    }
}

// Partial row sums of exp(scores/8). (verified R9)
__global__ __launch_bounds__(256) void k_rowsum(
    const bf16* __restrict__ qh, const bf16* __restrict__ kh,
    float* __restrict__ rs)
{
    const int lane = threadIdx.x & 63;
    const int w    = threadIdx.x >> 6;
    const int lr   = lane & 15;
    const int lg   = lane >> 4;
    const int h    = blockIdx.y;
    const int part = blockIdx.z;
    const int qw   = blockIdx.x * 256 + w * 64;

    const bf16* qb = qh + (size_t)h * (S * DK);
    const bf16* kb = kh + (size_t)h * (S * DK);
    bf16x8 aq[4][2];
#pragma unroll
    for (int qs = 0; qs < 4; ++qs) {
        aq[qs][0] = load_frag(qb + (size_t)(qw + qs * 16 + lr) * DK + lg * 8);
        aq[qs][1] = load_frag(qb + (size_t)(qw + qs * 16 + lr) * DK + 32 + lg * 8);
    }

    float s[4] = {0.f, 0.f, 0.f, 0.f};
    for (int kp = part * RCHUNK; kp < part * RCHUNK + RCHUNK; kp += 16) {
        bf16x8 b0 = load_frag(kb + (size_t)(kp + lr) * DK + lg * 8);
        bf16x8 b1 = load_frag(kb + (size_t)(kp + lr) * DK + 32 + lg * 8);
#pragma unroll
        for (int qs = 0; qs < 4; ++qs) {
            f32x4 d = {};
            d = __builtin_amdgcn_mfma_f32_16x16x32_bf16(b0, aq[qs][0], d, 0, 0, 0);
            d = __builtin_amdgcn_mfma_f32_16x16x32_bf16(b1, aq[qs][1], d, 0, 0, 0);
            s[qs] += __expf(d[0] * 0.125f) + __expf(d[1] * 0.125f) +
                     __expf(d[2] * 0.125f) + __expf(d[3] * 0.125f);
        }
    }
#pragma unroll
    for (int qs = 0; qs < 4; ++qs) {
        float v = s[qs];
        v += __shfl_xor(v, 16, 64);
        v += __shfl_xor(v, 32, 64);
        if (lg == 0)
            rs[((size_t)part * NH + h) * S + qw + qs * 16 + lr] = v;
    }
}

// R13-verified body (2-wave blocks, 32 q-rows/wave, 4-tile 256-col staging,
// V-prefetch, 1KB-row NONTEMPORAL flush — R15 proved NT is worth ~120us by
// keeping the P stream out of L2). SINGLE CHANGE vs R13: XCD-aware block
// swizzle — gid = (bid%8)*96 + bid/8 gives each XCD a contiguous 96-block
// range spanning only 2-3 heads, so its K/V working set (2-3 MB) fits the
// 4 MB per-XCD L2 (vs 12 MB unswizzled).
__global__ __launch_bounds__(128) void k_attn(
    const bf16* __restrict__ qh, const bf16* __restrict__ kh,
    const bf16* __restrict__ vt, const float* __restrict__ rs,
    void* __restrict__ doutv, bf16* __restrict__ ctx,
    const int* __restrict__ flag)
{
    __shared__ __align__(16) bf16 Plds[2][2][16][264];
    const int isf32 = flag[0];
    const int lane = threadIdx.x & 63;
    const int w    = threadIdx.x >> 6;           // 0..1
    const int lr   = lane & 15, lg = lane >> 4;
    // XCD swizzle: 768 blocks, 8 XCDs, 96 contiguous gids per XCD (bijective)
    const int gid  = (blockIdx.x & 7) * 96 + (blockIdx.x >> 3);
    const int h    = gid >> 6;                   // gid / 64
    const int q0w  = (gid & 63) * 64 + w * 32;   // wave's 32-q base

    const bf16* qb = qh + (size_t)h * (S * DK);
    const bf16* kb = kh + (size_t)h * (S * DK);
    const bf16* vb = vt + (size_t)h * (S * DK);

    bf16x8 aq[2][2];
    float  linv[2];
#pragma unroll
    for (int qs = 0; qs < 2; ++qs) {
        const int qr = q0w + qs * 16 + lr;
        aq[qs][0] = load_frag(qb + (size_t)qr * DK + lg * 8);
        aq[qs][1] = load_frag(qb + (size_t)qr * DK + 32 + lg * 8);
        float ssum = 0.f;
#pragma unroll
        for (int p = 0; p < RPARTS; ++p)
            ssum += rs[((size_t)p * NH + h) * S + qr];
        linv[qs] = -__logf(ssum);   // p = exp(s/8 + ln(1/sum))
    }

    float* poutF = (float*)doutv + (size_t)S * DM + (size_t)h * S * S;
    bf16*  poutB = (bf16*)doutv  + (size_t)S * DM + (size_t)h * S * S;

    f32x4 acc[2][4] = {};
    for (int g = 0; g < S / 256; ++g) {          // 16 groups of 4 tiles
#pragma unroll
        for (int tt = 0; tt < 4; ++tt) {
            const int kt = g * 256 + tt * 64;
            const int cb = tt * 64;              // column base in Plds
            // ---- V prefetch for this tile (independent of P) ----
            bf16x8 vv[4][2];
#pragma unroll
            for (int dt = 0; dt < 4; ++dt) {
                vv[dt][0] = load_frag(vb + (size_t)(dt * 16 + lr) * S + kt + lg * 8);
                vv[dt][1] = load_frag(vb + (size_t)(dt * 16 + lr) * S + kt + 32 + lg * 8);
            }
            // ---- QK^T (swapped: D rows = k, cols = q), exp, stage bf16 ----
#pragma unroll
            for (int sub = 0; sub < 4; ++sub) {
                const int kp = kt + sub * 16;
                bf16x8 b0 = load_frag(kb + (size_t)(kp + lr) * DK + lg * 8);
                bf16x8 b1 = load_frag(kb + (size_t)(kp + lr) * DK + 32 + lg * 8);
#pragma unroll
                for (int qs = 0; qs < 2; ++qs) {
                    f32x4 d = {};
                    d = __builtin_amdgcn_mfma_f32_16x16x32_bf16(b0, aq[qs][0], d, 0, 0, 0);
                    d = __builtin_amdgcn_mfma_f32_16x16x32_bf16(b1, aq[qs][1], d, 0, 0, 0);
                    bf16x4 pv;
                    pv[0] = (__bf16)__expf(__builtin_fmaf(d[0], 0.125f, linv[qs]));
                    pv[1] = (__bf16)__expf(__builtin_fmaf(d[1], 0.125f, linv[qs]));
                    pv[2] = (__bf16)__expf(__builtin_fmaf(d[2], 0.125f, linv[qs]));
                    pv[3] = (__bf16)__expf(__builtin_fmaf(d[3], 0.125f, linv[qs]));
                    *reinterpret_cast<bf16x4*>(
                        &Plds[w][qs][lr][cb + sub * 16 + 4 * lg]) = pv;
                }
            }
            // ---- PV on this 64-k tile (prefetched V, shared across qs) ----
            bf16x8 ap[2][2];
#pragma unroll
            for (int qs = 0; qs < 2; ++qs) {
                ap[qs][0] = *reinterpret_cast<const bf16x8*>(&Plds[w][qs][lr][cb + lg * 8]);
                ap[qs][1] = *reinterpret_cast<const bf16x8*>(&Plds[w][qs][lr][cb + 32 + lg * 8]);
            }
#pragma unroll
            for (int dt = 0; dt < 4; ++dt) {
#pragma unroll
                for (int qs = 0; qs < 2; ++qs) {
                    acc[qs][dt] = __builtin_amdgcn_mfma_f32_16x16x32_bf16(ap[qs][0], vv[dt][0], acc[qs][dt], 0, 0, 0);
                    acc[qs][dt] = __builtin_amdgcn_mfma_f32_16x16x32_bf16(ap[qs][1], vv[dt][1], acc[qs][dt], 0, 0, 0);
                }
            }
        }
        // ---- flush 4 tiles: 32 rows x 256 cols; 1KB row per store, NT ----
        const int ktbase = g * 256;
        if (isf32) {
#pragma unroll
            for (int j = 0; j < 32; ++j) {
                const int qs = j >> 4, rr = j & 15;
                bf16x4 x = *reinterpret_cast<const bf16x4*>(&Plds[w][qs][rr][lane * 4]);
                f32x4 o;
                o[0] = (float)x[0]; o[1] = (float)x[1];
                o[2] = (float)x[2]; o[3] = (float)x[3];
                __builtin_nontemporal_store(
                    o, reinterpret_cast<f32x4*>(
                           poutF + (size_t)(q0w + j) * S + ktbase + lane * 4));
            }
        } else {
#pragma unroll
            for (int j = 0; j < 32; ++j) {
                const int qs = j >> 4, rr = j & 15;
                bf16x4 x = *reinterpret_cast<const bf16x4*>(&Plds[w][qs][rr][lane * 4]);
                *reinterpret_cast<bf16x4*>(
                    poutB + (size_t)(q0w + j) * S + ktbase + lane * 4) = x;
            }
        }
    }
    // epilogue: ctx[q][h*64+d] (bf16), full k-range per q -> direct write
#pragma unroll
    for (int qs = 0; qs < 2; ++qs)
#pragma unroll
        for (int dt = 0; dt < 4; ++dt)
#pragma unroll
            for (int r = 0; r < 4; ++r)
                ctx[(size_t)(q0w + qs * 16 + 4 * lg + r) * DM + h * DK + dt * 16 + lr] =
                    __float2bfloat16(acc[qs][dt][r]);
}

extern "C" void kernel_launch(void* const* d_in, const int* in_sizes, int n_in,
                              void* d_out, int out_size, void* d_ws, size_t ws_size,
                              hipStream_t stream) {
    char* wsb = (char*)d_ws;
    int*   flag = (int*)wsb;                                    // 16 B
    float* rs   = (float*)(wsb + 16);                           // RPARTS*NH*S f32
    bf16*  conv = (bf16*)(wsb + 16 + (size_t)RPARTS * NH * S * 4);

    const size_t nQ = (size_t)S * DM, nW = (size_t)DM * DM, nB = DM;
    bf16* Qc  = conv;
    bf16* Kc  = Qc + nQ;
    bf16* Vc  = Kc + nQ;
    bf16* Wqc = Vc + nQ;
    bf16* Wkc = Wqc + nW;
    bf16* Wvc = Wkc + nW;
    bf16* Woc = Wvc + nW;
    bf16* bqc = Woc + nW;
    bf16* bkc = bqc + nB;
    bf16* bvc = bkc + nB;
    bf16* boc = bvc + nB;
    bf16* qh  = boc + nB;
    bf16* kh  = qh + nQ;
    bf16* vt  = kh + nQ;
    // alias (Qc dead after projections): ctx = nQ bf16
    bf16* ctx = Qc;

    const size_t need = (size_t)((char*)(vt + nQ) - wsb);
    if (ws_size < need) return;

    dim3 blk(256);
    k_detect<<<1, 64, 0, stream>>>((const unsigned int*)d_in[0], flag);

    CastArgs ca;
    ca.s[0] = d_in[0];  ca.d[0] = Qc;   ca.n[0] = (int)nQ;
    ca.s[1] = d_in[1];  ca.d[1] = Kc;   ca.n[1] = (int)nQ;
    ca.s[2] = d_in[2];  ca.d[2] = Vc;   ca.n[2] = (int)nQ;
    ca.s[3] = d_in[3];  ca.d[3] = Wqc;  ca.n[3] = (int)nW;
    ca.s[4] = d_in[5];  ca.d[4] = Wkc;  ca.n[4] = (int)nW;
    ca.s[5] = d_in[7];  ca.d[5] = Wvc;  ca.n[5] = (int)nW;
    ca.s[6] = d_in[9];  ca.d[6] = Woc;  ca.n[6] = (int)nW;
    ca.s[7] = d_in[4];  ca.d[7] = bqc;  ca.n[7] = (int)nB;
    ca.s[8] = d_in[6];  ca.d[8] = bkc;  ca.n[8] = (int)nB;
    ca.s[9] = d_in[8];  ca.d[9] = bvc;  ca.n[9] = (int)nB;
    ca.s[10] = d_in[10]; ca.d[10] = boc; ca.n[10] = (int)nB;
    k_cast_all<<<dim3(512, 11), blk, 0, stream>>>(ca, flag);

    k_proj_qkv<<<dim3(S / 64, DM / 64, 3), blk, 0, stream>>>(
        Qc, Kc, Vc, Wqc, Wkc, Wvc, bqc, bkc, bvc, qh, kh, vt, flag);
    k_rowsum<<<dim3(S / 256, NH, RPARTS), blk, 0, stream>>>(qh, kh, rs);
    k_attn<<<dim3(768), dim3(128), 0, stream>>>(qh, kh, vt, rs, d_out, ctx, flag);
    k_proj_out<<<dim3(S / 64, DM / 64), blk, 0, stream>>>(ctx, Woc, boc, d_out, flag);
}